// Round 5
// baseline (5786.075 us; speedup 1.0000x reference)
//
#include <hip/hip_runtime.h>
#include <hip/hip_bf16.h>

#define N_USERS 100000
#define N_ITEMS 50000
#define N_NODES 150000
#define N_EDGES 4800000
#define DIM 64
#define N_LAYERS 3
#define OUT_STRIDE 256   // DIM * (N_LAYERS+1)
#define EPS 1e-12f

#define NBUCK 1172       // ceil(150000/128) buckets of 128 rows
#define NBIN  1280       // padded bin count (= 256*5) for scans
#define TILE_E 8192      // edges per multisplit block
#define N_TILES 586      // ceil(N_EDGES / TILE_E)

// ---------------------------------------------------------------------------
// concat: write ego0 = [user_emb; item_emb] into out slice 0 (cols 0:64), f4
// ---------------------------------------------------------------------------
__global__ void concat_kernel(const float4* __restrict__ user_emb,
                              const float4* __restrict__ item_emb,
                              float4* __restrict__ out) {
    const int total = N_NODES * (DIM / 4);           // 2.4M float4
    for (int i = blockIdx.x * blockDim.x + threadIdx.x; i < total;
         i += gridDim.x * blockDim.x) {
        int node = i >> 4;            // 16 float4 per node row
        int q    = i & 15;
        float4 v = (node < N_USERS) ? user_emb[i] : item_emb[i - N_USERS * 16];
        out[node * (OUT_STRIDE / 4) + q] = v;
    }
}

// ---------------------------------------------------------------------------
// bucket histogram: LDS-aggregated per block, then one atomic per bin
// ---------------------------------------------------------------------------
__global__ __launch_bounds__(256)
void bucket_hist_kernel(const int* __restrict__ rows, int* __restrict__ bhist) {
    __shared__ int lh[NBIN];
    for (int i = threadIdx.x; i < NBIN; i += 256) lh[i] = 0;
    __syncthreads();
    for (int e = blockIdx.x * blockDim.x + threadIdx.x; e < N_EDGES;
         e += gridDim.x * blockDim.x)
        atomicAdd(&lh[rows[e] >> 7], 1);
    __syncthreads();
    for (int i = threadIdx.x; i < NBIN; i += 256)
        if (lh[i]) atomicAdd(&bhist[i], lh[i]);
}

// ---------------------------------------------------------------------------
// bucket scan: single block, 5 bins/thread seq + Hillis-Steele over 256
// writes bptr[0..NBIN] (exclusive, sentinel = N_EDGES) and bcur copy
// ---------------------------------------------------------------------------
__global__ __launch_bounds__(256)
void bucket_scan_kernel(const int* __restrict__ bhist,
                        int* __restrict__ bptr,
                        int* __restrict__ bcur) {
    __shared__ int tot[256];
    const int tid  = threadIdx.x;
    const int base = tid * 5;
    int c[5]; int s = 0;
#pragma unroll
    for (int k = 0; k < 5; ++k) { c[k] = bhist[base + k]; s += c[k]; }
    tot[tid] = s;
    __syncthreads();
    for (int off = 1; off < 256; off <<= 1) {
        int t = (tid >= off) ? tot[tid - off] : 0;
        __syncthreads();
        tot[tid] += t;
        __syncthreads();
    }
    int excl = tot[tid] - s;
#pragma unroll
    for (int k = 0; k < 5; ++k) {
        bptr[base + k] = excl;
        bcur[base + k] = excl;
        excl += c[k];
    }
    if (tid == 255) bptr[NBIN] = excl;   // == N_EDGES
}

// ---------------------------------------------------------------------------
// multisplit: bucket-sort TILE_E edges in LDS, flush coalesced runs to staged.
// staged entry (8B): [val f32 | roff(7b) << 18 | col(18b)]
// ---------------------------------------------------------------------------
__global__ __launch_bounds__(256)
void multisplit_kernel(const int* __restrict__ rows,
                       const int* __restrict__ cols,
                       const float* __restrict__ vals,
                       int* __restrict__ bcur,
                       unsigned long long* __restrict__ staged) {
    __shared__ int lhist[NBIN];                  // per-tile bucket counts
    __shared__ unsigned short lstart[NBIN + 1];  // per-tile bucket starts
    __shared__ int lcg[NBIN];                    // cursor, then global dst
    __shared__ int ltot[256];
    __shared__ unsigned long long sorted[TILE_E];

    const int tid  = threadIdx.x;
    const int base = blockIdx.x * TILE_E;
    const int cnt  = min(TILE_E, N_EDGES - base);

    for (int i = tid; i < NBIN; i += 256) lhist[i] = 0;
    __syncthreads();
    for (int i = tid; i < cnt; i += 256)
        atomicAdd(&lhist[rows[base + i] >> 7], 1);
    __syncthreads();

    // scan 1280 bins (5/thread + block scan)
    {
        const int b5 = tid * 5;
        int c[5]; int s = 0;
#pragma unroll
        for (int k = 0; k < 5; ++k) { c[k] = lhist[b5 + k]; s += c[k]; }
        ltot[tid] = s;
        __syncthreads();
        for (int off = 1; off < 256; off <<= 1) {
            int t = (tid >= off) ? ltot[tid - off] : 0;
            __syncthreads();
            ltot[tid] += t;
            __syncthreads();
        }
        int excl = ltot[tid] - s;
#pragma unroll
        for (int k = 0; k < 5; ++k) {
            lstart[b5 + k] = (unsigned short)excl;
            lcg   [b5 + k] = excl;
            excl += c[k];
        }
        if (tid == 255) lstart[NBIN] = (unsigned short)cnt;
        __syncthreads();
    }

    // place into LDS, bucket-sorted
    for (int i = tid; i < cnt; i += 256) {
        int   r = rows[base + i];
        int   c = cols[base + i];
        float v = vals[base + i];
        int   b = r >> 7;
        int pos = atomicAdd(&lcg[b], 1);
        unsigned meta = ((unsigned)(r & 127) << 18) | (unsigned)c;
        sorted[pos] = ((unsigned long long)__float_as_uint(v) << 32) | meta;
    }
    __syncthreads();

    // reserve global ranges (one atomic per non-empty bucket); reuse lcg
    for (int b = tid; b < NBIN; b += 256) {
        int n = lhist[b];
        lcg[b] = n ? atomicAdd(&bcur[b], n) : 0;
    }
    __syncthreads();

    // flush: slot i -> bucket b = largest b with lstart[b] <= i (upper_bound-1)
    for (int i = tid; i < cnt; i += 256) {
        int lo = 0, hi = NBIN;
        while (lo < hi) {
            int mid = (lo + hi + 1) >> 1;
            if ((int)lstart[mid] <= i) lo = mid; else hi = mid - 1;
        }
        staged[lcg[lo] + (i - (int)lstart[lo])] = sorted[i];
    }
}

// ---------------------------------------------------------------------------
// spmm via per-bucket LDS accumulator: one block per bucket (128 rows x 64).
// Waves stream staged edges (scalar 8B metadata), gather x[col] 256B,
// ds_add into LDS, then flush 128 rows coalesced into out slice l+1.
// ---------------------------------------------------------------------------
__global__ __launch_bounds__(256, 2)
void spmm_accum_kernel(const int* __restrict__ bptr,
                       const unsigned long long* __restrict__ staged,
                       const float* __restrict__ xin,     // out + layer*64
                       float* __restrict__ xside) {       // out + (layer+1)*64
    __shared__ float accum[128 * DIM];   // 32KB
    const int tid  = threadIdx.x;
    const int lane = tid & 63;
    const int w    = tid >> 6;
    const int b    = blockIdx.x;

    float4* a4 = (float4*)accum;
    for (int i = tid; i < 128 * DIM / 4; i += 256)
        a4[i] = make_float4(0.f, 0.f, 0.f, 0.f);
    __syncthreads();

    const int start = bptr[b];
    const int end   = bptr[b + 1];
    const int n     = end - start;
    const int per   = (n + 3) >> 2;
    const int s0 = __builtin_amdgcn_readfirstlane(start + w * per);
    const int e0 = __builtin_amdgcn_readfirstlane(min(start + (w + 1) * per, end));

    int j = s0;
    for (; j + 8 <= e0; j += 8) {
        unsigned long long pk[8]; float g[8];
#pragma unroll
        for (int u = 0; u < 8; ++u) {
            pk[u] = staged[j + u];                       // uniform -> s_load
            unsigned col = (unsigned)pk[u] & 0x3FFFFu;
            g[u] = xin[col * OUT_STRIDE + lane];         // 256B coalesced
        }
#pragma unroll
        for (int u = 0; u < 8; ++u) {
            int   roff = ((unsigned)pk[u]) >> 18;
            float v    = __uint_as_float((unsigned)(pk[u] >> 32));
            atomicAdd(&accum[roff * DIM + lane], v * g[u]);   // ds_add_f32
        }
    }
    for (; j < e0; ++j) {
        unsigned long long p = staged[j];
        unsigned meta = (unsigned)p;
        int   roff = meta >> 18;
        float v    = __uint_as_float((unsigned)(p >> 32));
        float g    = xin[(meta & 0x3FFFFu) * OUT_STRIDE + lane];
        atomicAdd(&accum[roff * DIM + lane], v * g);
    }
    __syncthreads();

    const int rbase = b << 7;
    for (int rr = w; rr < 128; rr += 4) {
        int row = rbase + rr;
        if (row < N_NODES)
            xside[row * OUT_STRIDE + lane] = accum[rr * DIM + lane];
    }
}

// ---------------------------------------------------------------------------
// dense: rewrite slice l+1 in place:  new = lrelu(side@Wg+bg)+lrelu((ego*side)@Wb+bb)
// ---------------------------------------------------------------------------
__global__ __launch_bounds__(256)
void dense_kernel(const float* __restrict__ xego,   // out + layer*64 (read)
                  float* __restrict__ xside,        // out + (layer+1)*64 (rw)
                  const float* __restrict__ gc_w,
                  const float* __restrict__ gc_b,
                  const float* __restrict__ bi_w,
                  const float* __restrict__ bi_b,
                  int layer) {
    __shared__ float sh[4][2][DIM];
    const int lane  = threadIdx.x & 63;
    const int wslot = threadIdx.x >> 6;
    const int wave  = (blockIdx.x * blockDim.x + threadIdx.x) >> 6;
    const int nwave = (gridDim.x * blockDim.x) >> 6;

    float gwr[DIM], bwr[DIM];
#pragma unroll
    for (int k = 0; k < DIM; ++k) {
        gwr[k] = gc_w[layer * DIM * DIM + k * DIM + lane];
        bwr[k] = bi_w[layer * DIM * DIM + k * DIM + lane];
    }
    const float gb = gc_b[layer * DIM + lane];
    const float bb = bi_b[layer * DIM + lane];

    for (int node = wave; node < N_NODES; node += nwave) {
        float sv = xside[node * OUT_STRIDE + lane];
        float ev = xego [node * OUT_STRIDE + lane];
        sh[wslot][0][lane] = sv;
        sh[wslot][1][lane] = ev;
        float accg = gb, accb = bb;
        const float4* s4 = (const float4*)sh[wslot][0];
        const float4* e4 = (const float4*)sh[wslot][1];
#pragma unroll
        for (int k4 = 0; k4 < DIM / 4; ++k4) {
            float4 s = s4[k4];
            float4 e = e4[k4];
            accg = fmaf(s.x, gwr[4*k4+0], accg); accb = fmaf(s.x*e.x, bwr[4*k4+0], accb);
            accg = fmaf(s.y, gwr[4*k4+1], accg); accb = fmaf(s.y*e.y, bwr[4*k4+1], accb);
            accg = fmaf(s.z, gwr[4*k4+2], accg); accb = fmaf(s.z*e.z, bwr[4*k4+2], accb);
            accg = fmaf(s.w, gwr[4*k4+3], accg); accb = fmaf(s.w*e.w, bwr[4*k4+3], accb);
        }
        float se = accg > 0.0f ? accg : 0.01f * accg;
        float be = accb > 0.0f ? accb : 0.01f * accb;
        xside[node * OUT_STRIDE + lane] = se + be;   // unnormalized ego_{l+1}
    }
}

// ---------------------------------------------------------------------------
// final pass: L2-normalize out slices 1..3 in place (wave per node)
// ---------------------------------------------------------------------------
__global__ void norm_kernel(float* __restrict__ out) {
    const int lane  = threadIdx.x & 63;
    const int wave  = (blockIdx.x * blockDim.x + threadIdx.x) >> 6;
    const int nwave = (gridDim.x * blockDim.x) >> 6;
    for (int node = wave; node < N_NODES; node += nwave) {
#pragma unroll
        for (int s = 1; s <= N_LAYERS; ++s) {
            float v = out[node * OUT_STRIDE + s * DIM + lane];
            float e2 = v * v;
#pragma unroll
            for (int off = 32; off > 0; off >>= 1)
                e2 += __shfl_xor(e2, off, 64);
            out[node * OUT_STRIDE + s * DIM + lane] = v / fmaxf(sqrtf(e2), EPS);
        }
    }
}

// ---------------------------------------------------------------------------
extern "C" void kernel_launch(void* const* d_in, const int* in_sizes, int n_in,
                              void* d_out, int out_size, void* d_ws, size_t ws_size,
                              hipStream_t stream) {
    const int*   adj_rows = (const int*)  d_in[0];
    const int*   adj_cols = (const int*)  d_in[1];
    const float* adj_vals = (const float*)d_in[2];
    const float* user_emb = (const float*)d_in[3];
    const float* item_emb = (const float*)d_in[4];
    const float* gc_w     = (const float*)d_in[5];
    const float* gc_b     = (const float*)d_in[6];
    const float* bi_w     = (const float*)d_in[7];
    const float* bi_b     = (const float*)d_in[8];
    float* out = (float*)d_out;

    // ws layout (~38.5 MB)
    char* p = (char*)d_ws;
    unsigned long long* staged = (unsigned long long*)p; p += (size_t)N_EDGES * 8;
    int* bhist = (int*)p;  p += (size_t)NBIN * 4;
    int* bptr  = (int*)p;  p += (size_t)(NBIN + 1) * 4;
    int* bcur  = (int*)p;

    // slice 0 = raw ego0
    concat_kernel<<<dim3(2048), dim3(256), 0, stream>>>(
        (const float4*)user_emb, (const float4*)item_emb, (float4*)out);

    // bucket-sort edges by row>>7
    hipMemsetAsync(bhist, 0, (size_t)NBIN * 4, stream);
    bucket_hist_kernel<<<dim3(1024), dim3(256), 0, stream>>>(adj_rows, bhist);
    bucket_scan_kernel<<<dim3(1), dim3(256), 0, stream>>>(bhist, bptr, bcur);
    multisplit_kernel<<<dim3(N_TILES), dim3(256), 0, stream>>>(
        adj_rows, adj_cols, adj_vals, bcur, staged);

    // layers: per-bucket LDS-accum spmm, then dense in-place rewrite
    for (int layer = 0; layer < N_LAYERS; ++layer) {
        spmm_accum_kernel<<<dim3(NBUCK), dim3(256), 0, stream>>>(
            bptr, staged, out + layer * DIM, out + (layer + 1) * DIM);
        dense_kernel<<<dim3(768), dim3(256), 0, stream>>>(
            out + layer * DIM, out + (layer + 1) * DIM,
            gc_w, gc_b, bi_w, bi_b, layer);
    }

    // normalize slices 1..3 in place
    norm_kernel<<<dim3(2048), dim3(256), 0, stream>>>(out);
}

// Round 7
// 1348.962 us; speedup vs baseline: 4.2893x; 4.2893x over previous
//
#include <hip/hip_runtime.h>
#include <hip/hip_bf16.h>

#define N_USERS 100000
#define N_ITEMS 50000
#define N_NODES 150000
#define N_EDGES 4800000
#define DIM 64
#define N_LAYERS 3
#define OUT_STRIDE 256   // DIM * (N_LAYERS+1)
#define EPS 1e-12f

#define NBUCK 1172       // ceil(150000/128) buckets of 128 rows
#define NBIN  1280       // padded (= 256*5) for scans
#define TILE_E 8192      // edges per multisplit block
#define N_TILES 586      // ceil(N_EDGES / TILE_E)
#define HIST_NB 512      // blocks in bucket_hist
#define FIN_CAP 6144     // LDS staging in finalize (48KB; bucket mean 4096, sd 64)

// ---------------------------------------------------------------------------
// concat: write ego0 = [user_emb; item_emb] into out slice 0 (cols 0:64), f4
// ---------------------------------------------------------------------------
__global__ void concat_kernel(const float4* __restrict__ user_emb,
                              const float4* __restrict__ item_emb,
                              float4* __restrict__ out) {
    const int total = N_NODES * (DIM / 4);
    for (int i = blockIdx.x * blockDim.x + threadIdx.x; i < total;
         i += gridDim.x * blockDim.x) {
        int node = i >> 4;
        int q    = i & 15;
        float4 v = (node < N_USERS) ? user_emb[i] : item_emb[i - N_USERS * 16];
        out[node * (OUT_STRIDE / 4) + q] = v;
    }
}

// ---------------------------------------------------------------------------
// bucket histogram: per-block LDS hist -> private global row (NO atomics)
// ---------------------------------------------------------------------------
__global__ __launch_bounds__(256)
void bucket_hist_kernel(const int* __restrict__ rows, int* __restrict__ hist_pb) {
    __shared__ int lh[NBIN];
    const int tid = threadIdx.x;
    for (int i = tid; i < NBIN; i += 256) lh[i] = 0;
    __syncthreads();
    const int chunk = (N_EDGES + HIST_NB - 1) / HIST_NB;   // 9375
    const int s = blockIdx.x * chunk;
    const int e = min(s + chunk, N_EDGES);
    for (int i = s + tid; i < e; i += 256)
        atomicAdd(&lh[rows[i] >> 7], 1);
    __syncthreads();
    for (int i = tid; i < NBIN; i += 256)
        hist_pb[blockIdx.x * NBIN + i] = lh[i];
}

// reduce per-block hists -> bhist   (grid 5 x 256, thread = bin)
__global__ __launch_bounds__(256)
void reduce_hist_kernel(const int* __restrict__ hist_pb, int* __restrict__ bhist) {
    int bin = blockIdx.x * 256 + threadIdx.x;
    if (bin >= NBIN) return;
    int s = 0;
#pragma unroll 8
    for (int b = 0; b < HIST_NB; ++b) s += hist_pb[b * NBIN + bin];
    bhist[bin] = s;
}

// ---------------------------------------------------------------------------
// bucket scan: single block, 5 bins/thread seq + Hillis-Steele over 256
// ---------------------------------------------------------------------------
__global__ __launch_bounds__(256)
void bucket_scan_kernel(const int* __restrict__ bhist,
                        int* __restrict__ bptr,
                        int* __restrict__ bcur) {
    __shared__ int tot[256];
    const int tid  = threadIdx.x;
    const int base = tid * 5;
    int c[5]; int s = 0;
#pragma unroll
    for (int k = 0; k < 5; ++k) { c[k] = bhist[base + k]; s += c[k]; }
    tot[tid] = s;
    __syncthreads();
    for (int off = 1; off < 256; off <<= 1) {
        int t = (tid >= off) ? tot[tid - off] : 0;
        __syncthreads();
        tot[tid] += t;
        __syncthreads();
    }
    int excl = tot[tid] - s;
#pragma unroll
    for (int k = 0; k < 5; ++k) {
        bptr[base + k] = excl;
        bcur[base + k] = excl;
        excl += c[k];
    }
    if (tid == 255) bptr[NBIN] = excl;   // == N_EDGES
}

// ---------------------------------------------------------------------------
// multisplit: bucket-sort TILE_E edges in LDS, flush coalesced runs to staged.
// staged entry (8B): [val f32 | roff(7b) << 18 | col(18b)]
// ---------------------------------------------------------------------------
__global__ __launch_bounds__(256)
void multisplit_kernel(const int* __restrict__ rows,
                       const int* __restrict__ cols,
                       const float* __restrict__ vals,
                       int* __restrict__ bcur,
                       unsigned long long* __restrict__ staged) {
    __shared__ int lhist[NBIN];
    __shared__ unsigned short lstart[NBIN + 2];
    __shared__ int lcg[NBIN];
    __shared__ int ltot[256];
    __shared__ unsigned long long sorted[TILE_E];

    const int tid  = threadIdx.x;
    const int base = blockIdx.x * TILE_E;
    const int cnt  = min(TILE_E, N_EDGES - base);

    for (int i = tid; i < NBIN; i += 256) lhist[i] = 0;
    __syncthreads();
    for (int i = tid; i < cnt; i += 256)
        atomicAdd(&lhist[rows[base + i] >> 7], 1);
    __syncthreads();

    {
        const int b5 = tid * 5;
        int c[5]; int s = 0;
#pragma unroll
        for (int k = 0; k < 5; ++k) { c[k] = lhist[b5 + k]; s += c[k]; }
        ltot[tid] = s;
        __syncthreads();
        for (int off = 1; off < 256; off <<= 1) {
            int t = (tid >= off) ? ltot[tid - off] : 0;
            __syncthreads();
            ltot[tid] += t;
            __syncthreads();
        }
        int excl = ltot[tid] - s;
#pragma unroll
        for (int k = 0; k < 5; ++k) {
            lstart[b5 + k] = (unsigned short)excl;
            lcg   [b5 + k] = excl;
            excl += c[k];
        }
        if (tid == 255) lstart[NBIN] = (unsigned short)cnt;
        __syncthreads();
    }

    for (int i = tid; i < cnt; i += 256) {
        int   r = rows[base + i];
        int   c = cols[base + i];
        float v = vals[base + i];
        int   b = r >> 7;
        int pos = atomicAdd(&lcg[b], 1);
        unsigned meta = ((unsigned)(r & 127) << 18) | (unsigned)c;
        sorted[pos] = ((unsigned long long)__float_as_uint(v) << 32) | meta;
    }
    __syncthreads();

    for (int b = tid; b < NBIN; b += 256) {
        int n = lhist[b];
        lcg[b] = n ? atomicAdd(&bcur[b], n) : 0;
    }
    __syncthreads();

    for (int i = tid; i < cnt; i += 256) {
        int lo = 0, hi = NBIN;
        while (lo < hi) {
            int mid = (lo + hi + 1) >> 1;
            if ((int)lstart[mid] <= i) lo = mid; else hi = mid - 1;
        }
        staged[lcg[lo] + (i - (int)lstart[lo])] = sorted[i];
    }
}

// ---------------------------------------------------------------------------
// bucket_finalize: per-bucket in-place counting sort by row (LDS-staged),
// emits row_ptr directly (bptr[b] + local exclusive scan).
// ---------------------------------------------------------------------------
__global__ __launch_bounds__(256)
void bucket_finalize_kernel(const int* __restrict__ bptr,
                            unsigned long long* __restrict__ staged,
                            int* __restrict__ row_ptr) {
    __shared__ int lh[128], lsc[128], lcur[128];
    __shared__ unsigned long long buf[FIN_CAP];
    const int tid   = threadIdx.x;
    const int b     = blockIdx.x;
    const int start = bptr[b];
    const int n     = bptr[b + 1] - start;     // ~4096 +- 64; FIN_CAP is 32 sd

    if (tid < 128) lh[tid] = 0;
    __syncthreads();
    for (int i = tid; i < n; i += 256) {
        unsigned long long e = staged[start + i];
        buf[i] = e;
        atomicAdd(&lh[(int)((e >> 18) & 127)], 1);
    }
    __syncthreads();
    if (tid < 128) lsc[tid] = lh[tid];
    __syncthreads();
    for (int off = 1; off < 128; off <<= 1) {
        int t = 0;
        if (tid < 128 && tid >= off) t = lsc[tid - off];
        __syncthreads();
        if (tid < 128) lsc[tid] += t;
        __syncthreads();
    }
    if (tid < 128) {
        int excl = lsc[tid] - lh[tid];
        lcur[tid] = excl;
        int row = (b << 7) + tid;
        if (row < N_NODES) row_ptr[row] = start + excl;
    }
    if (b == NBUCK - 1 && tid == 0) row_ptr[N_NODES] = N_EDGES;
    __syncthreads();
    for (int i = tid; i < n; i += 256) {
        unsigned long long e = buf[i];
        int r = (int)((e >> 18) & 127);
        int pos = atomicAdd(&lcur[r], 1);
        staged[start + pos] = e;           // reads all done before barrier
    }
}

// ---------------------------------------------------------------------------
// spmm pull, float4 lanes: wave = one row; lanes = 4 edges x 16 dim-quads.
// Each vector load covers 4 edges (1KB). 32-edge unroll = 8 loads in flight.
// Metadata via wave-uniform scalar loads; per-lane select by grp (cndmask).
// ---------------------------------------------------------------------------
__device__ __forceinline__ void pick4(unsigned long long e0, unsigned long long e1,
                                      unsigned long long e2, unsigned long long e3,
                                      int grp, int& c, float& v) {
    int c0 = (int)(e0 & 0x3FFFF), c1 = (int)(e1 & 0x3FFFF);
    int c2 = (int)(e2 & 0x3FFFF), c3 = (int)(e3 & 0x3FFFF);
    float v0 = __uint_as_float((unsigned)(e0 >> 32));
    float v1 = __uint_as_float((unsigned)(e1 >> 32));
    float v2 = __uint_as_float((unsigned)(e2 >> 32));
    float v3 = __uint_as_float((unsigned)(e3 >> 32));
    c = (grp == 0) ? c0 : (grp == 1) ? c1 : (grp == 2) ? c2 : c3;
    v = (grp == 0) ? v0 : (grp == 1) ? v1 : (grp == 2) ? v2 : v3;
}

__global__ __launch_bounds__(256, 6)
void spmm_pull_f4_kernel(const int* __restrict__ row_ptr,
                         const unsigned long long* __restrict__ cv,
                         const float* __restrict__ xin,    // out + layer*64
                         float* __restrict__ xside) {      // out + (layer+1)*64
    const int lane = threadIdx.x & 63;
    const int grp  = lane >> 4;          // which edge of the quad
    const int sub  = lane & 15;          // float4 index within row
    const int wave  = __builtin_amdgcn_readfirstlane(
        (blockIdx.x * blockDim.x + threadIdx.x) >> 6);
    const int nwave = (gridDim.x * blockDim.x) >> 6;
    const float4* x4 = (const float4*)xin;

    for (int node = wave; node < N_NODES; node += nwave) {
        const int start = __builtin_amdgcn_readfirstlane(row_ptr[node]);
        const int end   = __builtin_amdgcn_readfirstlane(row_ptr[node + 1]);

        float4 acc = make_float4(0.f, 0.f, 0.f, 0.f);
        int j = start;
        for (; j + 32 <= end; j += 32) {           // 8 quads in flight
            float4 g[8]; float vv[8];
#pragma unroll
            for (int s = 0; s < 8; ++s) {
                unsigned long long e0 = cv[j + 4*s + 0];   // uniform -> s_load
                unsigned long long e1 = cv[j + 4*s + 1];
                unsigned long long e2 = cv[j + 4*s + 2];
                unsigned long long e3 = cv[j + 4*s + 3];
                int c; float v;
                pick4(e0, e1, e2, e3, grp, c, v);
                g[s]  = x4[(size_t)c * (OUT_STRIDE / 4) + sub];  // 1KB/instr
                vv[s] = v;
            }
#pragma unroll
            for (int s = 0; s < 8; ++s) {
                acc.x = fmaf(vv[s], g[s].x, acc.x);
                acc.y = fmaf(vv[s], g[s].y, acc.y);
                acc.z = fmaf(vv[s], g[s].z, acc.z);
                acc.w = fmaf(vv[s], g[s].w, acc.w);
            }
        }
        // tail: quads of 4 with uniform clamped indices + per-lane mask
        for (; j < end; j += 4) {
            int i1 = (j + 1 < end) ? j + 1 : end - 1;
            int i2 = (j + 2 < end) ? j + 2 : end - 1;
            int i3 = (j + 3 < end) ? j + 3 : end - 1;
            unsigned long long e0 = cv[j];
            unsigned long long e1 = cv[i1];
            unsigned long long e2 = cv[i2];
            unsigned long long e3 = cv[i3];
            int c; float v;
            pick4(e0, e1, e2, e3, grp, c, v);
            if (j + grp >= end) v = 0.f;
            float4 g = x4[(size_t)c * (OUT_STRIDE / 4) + sub];
            acc.x = fmaf(v, g.x, acc.x);
            acc.y = fmaf(v, g.y, acc.y);
            acc.z = fmaf(v, g.z, acc.z);
            acc.w = fmaf(v, g.w, acc.w);
        }
        // reduce across the 4 edge-groups (lanes differing in bits 4,5)
#pragma unroll
        for (int m = 16; m <= 32; m <<= 1) {
            acc.x += __shfl_xor(acc.x, m, 64);
            acc.y += __shfl_xor(acc.y, m, 64);
            acc.z += __shfl_xor(acc.z, m, 64);
            acc.w += __shfl_xor(acc.w, m, 64);
        }
        if (lane < 16)
            ((float4*)(xside + (size_t)node * OUT_STRIDE))[sub] = acc;
    }
}

// ---------------------------------------------------------------------------
// dense (+ fused norms): new = lrelu(side@Wg+bg)+lrelu((ego*side)@Wb+bb)
// NI: L2-normalize xego slice in place. NO: write result normalized.
// ---------------------------------------------------------------------------
template<bool NI, bool NO>
__global__ __launch_bounds__(256)
void dense_kernel(float* __restrict__ xego,         // out + layer*64
                  float* __restrict__ xside,        // out + (layer+1)*64 (rw)
                  const float* __restrict__ gc_w,
                  const float* __restrict__ gc_b,
                  const float* __restrict__ bi_w,
                  const float* __restrict__ bi_b,
                  int layer) {
    __shared__ float sh[4][2][DIM];
    const int lane  = threadIdx.x & 63;
    const int wslot = threadIdx.x >> 6;
    const int wave  = (blockIdx.x * blockDim.x + threadIdx.x) >> 6;
    const int nwave = (gridDim.x * blockDim.x) >> 6;

    float gwr[DIM], bwr[DIM];
#pragma unroll
    for (int k = 0; k < DIM; ++k) {
        gwr[k] = gc_w[layer * DIM * DIM + k * DIM + lane];
        bwr[k] = bi_w[layer * DIM * DIM + k * DIM + lane];
    }
    const float gb = gc_b[layer * DIM + lane];
    const float bb = bi_b[layer * DIM + lane];

    for (int node = wave; node < N_NODES; node += nwave) {
        float sv = xside[node * OUT_STRIDE + lane];
        float ev = xego [node * OUT_STRIDE + lane];
        sh[wslot][0][lane] = sv;
        sh[wslot][1][lane] = ev;
        float accg = gb, accb = bb;
        const float4* s4 = (const float4*)sh[wslot][0];
        const float4* e4 = (const float4*)sh[wslot][1];
#pragma unroll
        for (int k4 = 0; k4 < DIM / 4; ++k4) {
            float4 s = s4[k4];
            float4 e = e4[k4];
            accg = fmaf(s.x, gwr[4*k4+0], accg); accb = fmaf(s.x*e.x, bwr[4*k4+0], accb);
            accg = fmaf(s.y, gwr[4*k4+1], accg); accb = fmaf(s.y*e.y, bwr[4*k4+1], accb);
            accg = fmaf(s.z, gwr[4*k4+2], accg); accb = fmaf(s.z*e.z, bwr[4*k4+2], accb);
            accg = fmaf(s.w, gwr[4*k4+3], accg); accb = fmaf(s.w*e.w, bwr[4*k4+3], accb);
        }
        if (NI) {   // normalize the INPUT slice in place (raw ev already consumed)
            float e2 = ev * ev;
#pragma unroll
            for (int off = 32; off > 0; off >>= 1) e2 += __shfl_xor(e2, off, 64);
            xego[node * OUT_STRIDE + lane] = ev / fmaxf(sqrtf(e2), EPS);
        }
        float se = accg > 0.0f ? accg : 0.01f * accg;
        float be = accb > 0.0f ? accb : 0.01f * accb;
        float r  = se + be;
        if (NO) {   // last layer: write normalized directly
            float r2 = r * r;
#pragma unroll
            for (int off = 32; off > 0; off >>= 1) r2 += __shfl_xor(r2, off, 64);
            r = r / fmaxf(sqrtf(r2), EPS);
        }
        xside[node * OUT_STRIDE + lane] = r;
    }
}

// ---------------------------------------------------------------------------
extern "C" void kernel_launch(void* const* d_in, const int* in_sizes, int n_in,
                              void* d_out, int out_size, void* d_ws, size_t ws_size,
                              hipStream_t stream) {
    const int*   adj_rows = (const int*)  d_in[0];
    const int*   adj_cols = (const int*)  d_in[1];
    const float* adj_vals = (const float*)d_in[2];
    const float* user_emb = (const float*)d_in[3];
    const float* item_emb = (const float*)d_in[4];
    const float* gc_w     = (const float*)d_in[5];
    const float* gc_b     = (const float*)d_in[6];
    const float* bi_w     = (const float*)d_in[7];
    const float* bi_b     = (const float*)d_in[8];
    float* out = (float*)d_out;

    // ws layout (~42 MB)
    char* p = (char*)d_ws;
    unsigned long long* staged = (unsigned long long*)p; p += (size_t)N_EDGES * 8; // 38.4MB
    int* hist_pb = (int*)p; p += (size_t)HIST_NB * NBIN * 4;                       // 2.6MB
    int* bhist   = (int*)p; p += (size_t)NBIN * 4;
    int* bptr    = (int*)p; p += (size_t)(NBIN + 1) * 4;
    int* bcur    = (int*)p; p += (size_t)NBIN * 4;
    int* row_ptr = (int*)p;                                                        // 600KB

    concat_kernel<<<dim3(2048), dim3(256), 0, stream>>>(
        (const float4*)user_emb, (const float4*)item_emb, (float4*)out);

    // CSR build: hist (no atomics) -> reduce -> scan -> multisplit -> finalize
    bucket_hist_kernel<<<dim3(HIST_NB), dim3(256), 0, stream>>>(adj_rows, hist_pb);
    reduce_hist_kernel<<<dim3(5), dim3(256), 0, stream>>>(hist_pb, bhist);
    bucket_scan_kernel<<<dim3(1), dim3(256), 0, stream>>>(bhist, bptr, bcur);
    multisplit_kernel<<<dim3(N_TILES), dim3(256), 0, stream>>>(
        adj_rows, adj_cols, adj_vals, bcur, staged);
    bucket_finalize_kernel<<<dim3(NBUCK), dim3(256), 0, stream>>>(
        bptr, staged, row_ptr);

    // layers
    spmm_pull_f4_kernel<<<dim3(2048), dim3(256), 0, stream>>>(
        row_ptr, staged, out + 0 * DIM, out + 1 * DIM);
    dense_kernel<false, false><<<dim3(768), dim3(256), 0, stream>>>(
        out + 0 * DIM, out + 1 * DIM, gc_w, gc_b, bi_w, bi_b, 0);

    spmm_pull_f4_kernel<<<dim3(2048), dim3(256), 0, stream>>>(
        row_ptr, staged, out + 1 * DIM, out + 2 * DIM);
    dense_kernel<true, false><<<dim3(768), dim3(256), 0, stream>>>(
        out + 1 * DIM, out + 2 * DIM, gc_w, gc_b, bi_w, bi_b, 1);

    spmm_pull_f4_kernel<<<dim3(2048), dim3(256), 0, stream>>>(
        row_ptr, staged, out + 2 * DIM, out + 3 * DIM);
    dense_kernel<true, true><<<dim3(768), dim3(256), 0, stream>>>(
        out + 2 * DIM, out + 3 * DIM, gc_w, gc_b, bi_w, bi_b, 2);
}